// Round 2
// baseline (1450.972 us; speedup 1.0000x reference)
//
#include <hip/hip_runtime.h>
#include <math.h>

constexpr int KW      = 56;
constexpr int NB      = 1792;
constexpr int QKV_CH  = 128;
constexpr int SIM_CH  = 24;
constexpr float EPS   = 1e-5f;

// symmetric channel-pair tables (c <= c') for 4-channel Gram matrices
constexpr int   PA[10]  = {0,0,0,0,1,1,1,2,2,3};
constexpr int   PB[10]  = {0,1,2,3,1,2,3,2,3,3};
constexpr float PMf[10] = {1,2,2,2,1,2,2,1,2,1};

// ---------------- setup: rel-derived tables (once per launch) ----------------
// Rq[i*4+c]   = sum_{t=i}^{i+55} rel[c][t]            (c = q rows 0..3)
// Rk[j*4+c]   = sum_{t=j}^{j+55} rel[4+c][t]
// E2q[i*10+p] = sum_{t=i}^{i+55} rel[PA]*rel[PB]      (rows 0..3)
// E2k[j*10+p] = same, rows 4..7
// Tq[d*4+c]   = rel[c][d]      (d<111, row 111 zero-pad)
// Tk[d*4+c]   = rel[4+c][d]
// Tv[d*8+cc]  = rel[8+cc][d]
__global__ void k_setup(const float* __restrict__ rel, float* __restrict__ tabs) {
    const int t = threadIdx.x;
    float* Rq  = tabs;
    float* Rk  = tabs + 224;
    float* E2q = tabs + 448;
    float* E2k = tabs + 1008;
    float* Tq  = tabs + 1568;
    float* Tk  = tabs + 2016;
    float* Tv  = tabs + 2464;
    for (int idx = t; idx < 448; idx += 256) {
        int which = idx / 224, r = idx % 224;
        int i = r >> 2, c = r & 3;
        const float* src = rel + (which * 4 + c) * 111;
        float s = 0.f;
        for (int tt = 0; tt < 56; ++tt) s += src[i + tt];
        (which ? Rk : Rq)[r] = s;
    }
    for (int idx = t; idx < 1120; idx += 256) {
        int which = idx / 560, r = idx % 560;
        int i = r / 10, p = r % 10;
        const float* sa = rel + (which * 4 + PA[p]) * 111;
        const float* sb = rel + (which * 4 + PB[p]) * 111;
        float s = 0.f;
        for (int tt = 0; tt < 56; ++tt) s += sa[i + tt] * sb[i + tt];
        (which ? E2k : E2q)[r] = s;
    }
    for (int idx = t; idx < 896; idx += 256) {
        int which = idx / 448, r = idx % 448;
        int d = r >> 2, c = r & 3;
        float v = (d < 111) ? rel[(which * 4 + c) * 111 + d] : 0.f;
        (which ? Tk : Tq)[r] = v;
    }
    for (int idx = t; idx < 896; idx += 256) {
        int d = idx >> 3, cc = idx & 7;
        Tv[idx] = (d < 111) ? rel[(8 + cc) * 111 + d] : 0.f;
    }
}

// ---------------- Kernel A: qkv[b][i][o] = w @ x + per-channel stats ----------
__global__ __launch_bounds__(256) void k_qkv(const float* __restrict__ x,
                                             const float* __restrict__ w,
                                             float* __restrict__ qkv,
                                             float* __restrict__ sums) {
    __shared__ float xs[64 * KW];     // xs[c*56+i]
    __shared__ float wt[64 * 128];    // wt[c*128+o]
    __shared__ float s1[128], s2[128];
    const int b = blockIdx.x, t = threadIdx.x;

    if (t < 128) { s1[t] = 0.f; s2[t] = 0.f; }
    // stage x: 3584 floats = 896 float4s, coalesced
    for (int idx = t; idx < 896; idx += 256) {
        int c = idx / 14, r = idx % 14;
        float4 v = *(const float4*)&x[c * 100352 + b * 56 + r * 4];
        *(float4*)&xs[c * 56 + r * 4] = v;
    }
    // stage w transposed: read float4 along c (coalesced), scatter b32 (conflict-free along o)
    for (int idx = t; idx < 2048; idx += 256) {
        int o = idx >> 4, cq = idx & 15;
        float4 v = *(const float4*)&w[o * 64 + cq * 4];
        wt[(cq * 4 + 0) * 128 + o] = v.x;
        wt[(cq * 4 + 1) * 128 + o] = v.y;
        wt[(cq * 4 + 2) * 128 + o] = v.z;
        wt[(cq * 4 + 3) * 128 + o] = v.w;
    }
    __syncthreads();

    if (t < 224) {
        const int ob = t & 31, ib = t >> 5;     // 32 o-quads x 7 i-octets
        float4 acc[8];
#pragma unroll
        for (int i = 0; i < 8; ++i) acc[i] = make_float4(0.f, 0.f, 0.f, 0.f);
        for (int c = 0; c < 64; ++c) {
            float4 wv = *(const float4*)&wt[c * 128 + (ob << 2)];
            float4 x0 = *(const float4*)&xs[c * 56 + (ib << 3)];
            float4 x1 = *(const float4*)&xs[c * 56 + (ib << 3) + 4];
            float xv[8] = {x0.x, x0.y, x0.z, x0.w, x1.x, x1.y, x1.z, x1.w};
#pragma unroll
            for (int i = 0; i < 8; ++i) {
                acc[i].x += xv[i] * wv.x;
                acc[i].y += xv[i] * wv.y;
                acc[i].z += xv[i] * wv.z;
                acc[i].w += xv[i] * wv.w;
            }
        }
#pragma unroll
        for (int i = 0; i < 8; ++i) {
            *(float4*)&qkv[b * 7168 + (ib * 8 + i) * 128 + ob * 4] = acc[i];
        }
        const float* af = reinterpret_cast<const float*>(acc);
#pragma unroll
        for (int oo = 0; oo < 4; ++oo) {
            float ps = 0.f, ps2 = 0.f;
#pragma unroll
            for (int i = 0; i < 8; ++i) {
                float v = af[i * 4 + oo];
                ps += v; ps2 += v * v;
            }
            atomicAdd(&s1[ob * 4 + oo], ps);
            atomicAdd(&s2[ob * 4 + oo], ps2);
        }
    }
    __syncthreads();
    if (t < 128) {
        atomicAdd(&sums[t], s1[t]);
        atomicAdd(&sums[128 + t], s2[t]);
    }
}

// ---------------- coef finalize ----------------
__global__ void k_coef(const float* __restrict__ sums, const float* __restrict__ g,
                       const float* __restrict__ bb, float* __restrict__ coef,
                       int nch, float invM) {
    int o = blockIdx.x * blockDim.x + threadIdx.x;
    if (o < nch) {
        float mean = sums[o] * invM;
        float var  = fmaxf(sums[nch + o] * invM - mean * mean, 0.f);
        float sc   = g[o] * rsqrtf(var + EPS);
        coef[o] = sc;
        coef[nch + o] = bb[o] - mean * sc;
    }
}

// ---------------- sim stats via Gram matrices (one wave per (b,g)) -----------
__global__ __launch_bounds__(256) void k_simstats(const float* __restrict__ qkv,
                                                  const float* __restrict__ qcoef,
                                                  const float* __restrict__ Rq,
                                                  const float* __restrict__ Rk,
                                                  const float* __restrict__ E2q,
                                                  const float* __restrict__ E2k,
                                                  float* __restrict__ ssum) {
    const int wid = threadIdx.x >> 6, lane = threadIdx.x & 63;
    const int unit = blockIdx.x * 4 + wid;
    const int b = unit >> 3, g = unit & 7;
    const int iL = lane < 56 ? lane : 55;
    const float valid = lane < 56 ? 1.f : 0.f;

    const float* row = qkv + b * 7168 + iL * 128 + g * 16;
    float4 q4 = *(const float4*)(row);
    float4 k4 = *(const float4*)(row + 4);
    const float4 aq = *(const float4*)&qcoef[g * 16];
    const float4 ak = *(const float4*)&qcoef[g * 16 + 4];
    const float4 cq = *(const float4*)&qcoef[QKV_CH + g * 16];
    const float4 ck = *(const float4*)&qcoef[QKV_CH + g * 16 + 4];
    float qv[4], kv[4];
    qv[0] = (q4.x * aq.x + cq.x) * valid;
    qv[1] = (q4.y * aq.y + cq.y) * valid;
    qv[2] = (q4.z * aq.z + cq.z) * valid;
    qv[3] = (q4.w * aq.w + cq.w) * valid;
    kv[0] = (k4.x * ak.x + ck.x) * valid;
    kv[1] = (k4.y * ak.y + ck.y) * valid;
    kv[2] = (k4.z * ak.z + ck.z) * valid;
    kv[3] = (k4.w * ak.w + ck.w) * valid;

    float4 rq = *(const float4*)&Rq[iL * 4];
    float4 rk = *(const float4*)&Rk[iL * 4];
    float e2q[10], e2k[10];
#pragma unroll
    for (int p = 0; p < 10; ++p) { e2q[p] = E2q[iL * 10 + p]; e2k[p] = E2k[iL * 10 + p]; }

    float red[32];
#pragma unroll
    for (int c = 0; c < 4; ++c) { red[c] = qv[c]; red[4 + c] = kv[c]; }
#pragma unroll
    for (int p = 0; p < 10; ++p) {
        red[8 + p]  = qv[PA[p]] * qv[PB[p]];
        red[18 + p] = kv[PA[p]] * kv[PB[p]];
    }
    {
        float rqa[4] = {rq.x, rq.y, rq.z, rq.w};
        float rka[4] = {rk.x, rk.y, rk.z, rk.w};
        float pq = 0.f, pk = 0.f, pq2 = 0.f, pk2 = 0.f;
#pragma unroll
        for (int c = 0; c < 4; ++c) { pq += qv[c] * rqa[c]; pk += kv[c] * rka[c]; }
#pragma unroll
        for (int p = 0; p < 10; ++p) {
            pq2 += PMf[p] * red[8 + p]  * e2q[p];
            pk2 += PMf[p] * red[18 + p] * e2k[p];
        }
        red[28] = pq; red[29] = pk; red[30] = pq2; red[31] = pk2;
    }
#pragma unroll
    for (int v = 0; v < 32; ++v) {
        float xv = red[v];
#pragma unroll
        for (int mk = 1; mk < 64; mk <<= 1) xv += __shfl_xor(xv, mk);
        red[v] = xv;
    }
    float sqk = 0.f, sqk2 = 0.f;
#pragma unroll
    for (int c = 0; c < 4; ++c) sqk += red[c] * red[4 + c];
#pragma unroll
    for (int p = 0; p < 10; ++p) sqk2 += PMf[p] * red[8 + p] * red[18 + p];
    float sqr  = 0.1f  * red[28];
    float skr  = 0.1f  * red[29];
    float sqr2 = 0.01f * red[30];
    float skr2 = 0.01f * red[31];
    if (lane == 0) {
        atomicAdd(&ssum[g], sqk);
        atomicAdd(&ssum[8 + g], sqr);
        atomicAdd(&ssum[16 + g], skr);
        atomicAdd(&ssum[SIM_CH + g], sqk2);
        atomicAdd(&ssum[SIM_CH + 8 + g], sqr2);
        atomicAdd(&ssum[SIM_CH + 16 + g], skr2);
    }
}

// ---------------- attention: one wave per (b,g), lane = row i ----------------
__global__ __launch_bounds__(256) void k_attn(const float* __restrict__ qkv,
                                              const float* __restrict__ qcoef,
                                              const float* __restrict__ scoef,
                                              const float* __restrict__ Tq,
                                              const float* __restrict__ Tk,
                                              const float* __restrict__ Tv,
                                              float* __restrict__ so,
                                              float* __restrict__ osums) {
    __shared__ float sm[4 * 1568];
    const int wid = threadIdx.x >> 6, lane = threadIdx.x & 63;
    const int unit = blockIdx.x * 4 + wid;
    const int b = unit >> 3, g = unit & 7;
    float* sl = sm + wid * 1568;       // [0,224) qT ; [224,672) kT_ext ; [672,1568) vT_ext
    const int iL = lane < 56 ? lane : 55;

    const float* row = qkv + b * 7168 + iL * 128 + g * 16;
    float4 q4  = *(const float4*)(row);
    float4 k4  = *(const float4*)(row + 4);
    float4 va4 = *(const float4*)(row + 8);
    float4 vb4 = *(const float4*)(row + 12);
    const float4 a0 = *(const float4*)&qcoef[g * 16];
    const float4 a1 = *(const float4*)&qcoef[g * 16 + 4];
    const float4 a2 = *(const float4*)&qcoef[g * 16 + 8];
    const float4 a3 = *(const float4*)&qcoef[g * 16 + 12];
    const float4 c0 = *(const float4*)&qcoef[QKV_CH + g * 16];
    const float4 c1 = *(const float4*)&qcoef[QKV_CH + g * 16 + 4];
    const float4 c2 = *(const float4*)&qcoef[QKV_CH + g * 16 + 8];
    const float4 c3 = *(const float4*)&qcoef[QKV_CH + g * 16 + 12];
    float4 qh, kh, vha, vhb;
    qh.x  = q4.x  * a0.x + c0.x;  qh.y  = q4.y  * a0.y + c0.y;
    qh.z  = q4.z  * a0.z + c0.z;  qh.w  = q4.w  * a0.w + c0.w;
    kh.x  = k4.x  * a1.x + c1.x;  kh.y  = k4.y  * a1.y + c1.y;
    kh.z  = k4.z  * a1.z + c1.z;  kh.w  = k4.w  * a1.w + c1.w;
    vha.x = va4.x * a2.x + c2.x;  vha.y = va4.y * a2.y + c2.y;
    vha.z = va4.z * a2.z + c2.z;  vha.w = va4.w * a2.w + c2.w;
    vhb.x = vb4.x * a3.x + c3.x;  vhb.y = vb4.y * a3.y + c3.y;
    vhb.z = vb4.z * a3.z + c3.z;  vhb.w = vb4.w * a3.w + c3.w;
    if (lane < 56) {
        *(float4*)&sl[iL * 4] = qh;
        *(float4*)&sl[224 + iL * 4] = kh;
        *(float4*)&sl[224 + (iL + 56) * 4] = kh;
        *(float4*)&sl[672 + iL * 8] = vha;
        *(float4*)&sl[672 + iL * 8 + 4] = vhb;
        *(float4*)&sl[672 + (iL + 56) * 8] = vha;
        *(float4*)&sl[672 + (iL + 56) * 8 + 4] = vhb;
    }
    __syncthreads();

    const float aqk = scoef[g];
    const float aqr = scoef[8 + g] * 0.1f;
    const float akr = scoef[16 + g] * 0.1f;
    const float cc  = scoef[SIM_CH + g] + scoef[SIM_CH + 8 + g] + scoef[SIM_CH + 16 + g];

    float srow[56];
    float m = -1e30f;
#pragma unroll
    for (int s = 0; s < 56; ++s) {
        const float4 kk   = *(const float4*)&sl[224 + (iL + s) * 4];
        const float4 rqlo = *(const float4*)&Tq[(55 - s) * 4];
        const float4 rqhi = *(const float4*)&Tq[(111 - s) * 4];
        const float4 rklo = *(const float4*)&Tk[(55 + s) * 4];
        const float4 rkhi = *(const float4*)&Tk[(s >= 1 ? s - 1 : 0) * 4];
        float qk   = qh.x * kk.x + qh.y * kk.y + qh.z * kk.z + qh.w * kk.w;
        float qrlo = qh.x * rqlo.x + qh.y * rqlo.y + qh.z * rqlo.z + qh.w * rqlo.w;
        float qrhi = qh.x * rqhi.x + qh.y * rqhi.y + qh.z * rqhi.z + qh.w * rqhi.w;
        float krlo = kk.x * rklo.x + kk.y * rklo.y + kk.z * rklo.z + kk.w * rklo.w;
        float krhi = kk.x * rkhi.x + kk.y * rkhi.y + kk.z * rkhi.z + kk.w * rkhi.w;
        bool wrap = (iL + s) >= 56;
        float qr = wrap ? qrhi : qrlo;
        float kr = wrap ? krhi : krlo;
        float sval = qk * aqk + qr * aqr + kr * akr + cc;
        srow[s] = sval;
        m = fmaxf(m, sval);
    }

    float l = 0.f;
    float sv[8], se[8];
#pragma unroll
    for (int c = 0; c < 8; ++c) { sv[c] = 0.f; se[c] = 0.f; }
#pragma unroll
    for (int s = 0; s < 56; ++s) {
        float e = __expf(srow[s] - m);
        l += e;
        const float4 va = *(const float4*)&sl[672 + (iL + s) * 8];
        const float4 vb = *(const float4*)&sl[672 + (iL + s) * 8 + 4];
        sv[0] += e * va.x; sv[1] += e * va.y; sv[2] += e * va.z; sv[3] += e * va.w;
        sv[4] += e * vb.x; sv[5] += e * vb.y; sv[6] += e * vb.z; sv[7] += e * vb.w;
        const float4 r1lo = *(const float4*)&Tv[(55 - s) * 8];
        const float4 r2lo = *(const float4*)&Tv[(55 - s) * 8 + 4];
        const float4 r1hi = *(const float4*)&Tv[(111 - s) * 8];
        const float4 r2hi = *(const float4*)&Tv[(111 - s) * 8 + 4];
        bool wrap = (iL + s) >= 56;
        float elo = wrap ? 0.f : e;
        float ehi = wrap ? e : 0.f;
        se[0] += elo * r1lo.x + ehi * r1hi.x;
        se[1] += elo * r1lo.y + ehi * r1hi.y;
        se[2] += elo * r1lo.z + ehi * r1hi.z;
        se[3] += elo * r1lo.w + ehi * r1hi.w;
        se[4] += elo * r2lo.x + ehi * r2hi.x;
        se[5] += elo * r2lo.y + ehi * r2hi.y;
        se[6] += elo * r2lo.z + ehi * r2hi.z;
        se[7] += elo * r2lo.w + ehi * r2hi.w;
    }
    float inv = 1.f / l;
    float osv[8], ose[8];
#pragma unroll
    for (int c = 0; c < 8; ++c) {
        osv[c] = sv[c] * inv;
        ose[c] = se[c] * (0.1f * inv);
    }
    if (lane < 56) {
        float* op = so + b * 7168 + g * 16 * 56 + iL;
#pragma unroll
        for (int c = 0; c < 8; ++c) {
            op[(2 * c) * 56]     = osv[c];
            op[(2 * c + 1) * 56] = ose[c];
        }
    }
    const float valid = lane < 56 ? 1.f : 0.f;
    float red[32];
#pragma unroll
    for (int c = 0; c < 8; ++c) {
        red[c]      = osv[c] * valid;
        red[8 + c]  = ose[c] * valid;
        red[16 + c] = osv[c] * osv[c] * valid;
        red[24 + c] = ose[c] * ose[c] * valid;
    }
#pragma unroll
    for (int v = 0; v < 32; ++v) {
        float xv = red[v];
#pragma unroll
        for (int mk = 1; mk < 64; mk <<= 1) xv += __shfl_xor(xv, mk);
        red[v] = xv;
    }
    if (lane == 0) {
#pragma unroll
        for (int c = 0; c < 8; ++c) {
            atomicAdd(&osums[g * 16 + 2 * c],           red[c]);
            atomicAdd(&osums[g * 16 + 2 * c + 1],       red[8 + c]);
            atomicAdd(&osums[QKV_CH + g * 16 + 2 * c],     red[16 + c]);
            atomicAdd(&osums[QKV_CH + g * 16 + 2 * c + 1], red[24 + c]);
        }
    }
}

// ---------------- out-BN + pair-sum + transpose store ----------------
__global__ __launch_bounds__(256) void k_out(const float* __restrict__ so,
                                             const float* __restrict__ ocoef,
                                             float* __restrict__ out) {
    int idx = blockIdx.x * 256 + threadIdx.x;
    int t = idx % KW;
    int rest = idx / KW;
    int h = rest % KW;
    int rest2 = rest / KW;
    int d = rest2 & 31;
    int oc = rest2 >> 5;
    int b = d * KW + h;
    int o0 = 2 * oc;
    float v0 = so[(size_t)b * 7168 + o0 * KW + t];
    float v1 = so[(size_t)b * 7168 + (o0 + 1) * KW + t];
    v0 = v0 * ocoef[o0]     + ocoef[QKV_CH + o0];
    v1 = v1 * ocoef[o0 + 1] + ocoef[QKV_CH + o0 + 1];
    out[idx] = v0 + v1;
}

extern "C" void kernel_launch(void* const* d_in, const int* in_sizes, int n_in,
                              void* d_out, int out_size, void* d_ws, size_t ws_size,
                              hipStream_t stream) {
    const float* x     = (const float*)d_in[0];
    const float* wqkv  = (const float*)d_in[1];
    const float* rel   = (const float*)d_in[2];
    const float* g_qkv = (const float*)d_in[3];
    const float* b_qkv = (const float*)d_in[4];
    const float* g_sim = (const float*)d_in[5];
    const float* b_sim = (const float*)d_in[6];
    const float* g_out = (const float*)d_in[7];
    const float* b_out = (const float*)d_in[8];
    float* out = (float*)d_out;
    float* ws = (float*)d_ws;

    float* qkv_raw  = ws;                       // [b][i][o] 12,845,056 floats
    float* so_raw   = ws + 12845056;            // [b][o][i] 12,845,056 floats
    float* stats    = ws + 25690112;
    float* qkv_sums = stats;                    // 256
    float* sim_sums = stats + 256;              // 48
    float* out_sums = stats + 304;              // 256
    float* qkv_coef = stats + 560;              // 256
    float* sim_coef = stats + 816;              // 48
    float* out_coef = stats + 864;              // 256
    float* tabs     = ws + 25690112 + 1120;     // 3360 floats of rel tables
    float* Rq  = tabs;
    float* Rk  = tabs + 224;
    float* E2q = tabs + 448;
    float* E2k = tabs + 1008;
    float* Tq  = tabs + 1568;
    float* Tk  = tabs + 2016;
    float* Tv  = tabs + 2464;

    hipMemsetAsync(stats, 0, 560 * sizeof(float), stream);
    k_setup<<<1, 256, 0, stream>>>(rel, tabs);

    k_qkv<<<NB, 256, 0, stream>>>(x, wqkv, qkv_raw, qkv_sums);
    k_coef<<<1, 128, 0, stream>>>(qkv_sums, g_qkv, b_qkv, qkv_coef, QKV_CH,
                                  1.0f / 100352.0f);
    k_simstats<<<3584, 256, 0, stream>>>(qkv_raw, qkv_coef, Rq, Rk, E2q, E2k,
                                         sim_sums);
    k_coef<<<1, 128, 0, stream>>>(sim_sums, g_sim, b_sim, sim_coef, SIM_CH,
                                  1.0f / 5619712.0f);
    k_attn<<<3584, 256, 0, stream>>>(qkv_raw, qkv_coef, sim_coef, Tq, Tk, Tv,
                                     so_raw, out_sums);
    k_coef<<<1, 128, 0, stream>>>(out_sums, g_out, b_out, out_coef, QKV_CH,
                                  1.0f / 100352.0f);
    k_out<<<25088, 256, 0, stream>>>(so_raw, out_coef, out);
}

// Round 3
// 507.762 us; speedup vs baseline: 2.8576x; 2.8576x over previous
//
#include <hip/hip_runtime.h>
#include <math.h>

constexpr int KW      = 56;
constexpr int NB      = 1792;
constexpr int QKV_CH  = 128;
constexpr int SIM_CH  = 24;
constexpr float EPS   = 1e-5f;

constexpr int   PA[10]  = {0,0,0,0,1,1,1,2,2,3};
constexpr int   PB[10]  = {0,1,2,3,1,2,3,2,3,3};
constexpr float PMf[10] = {1,2,2,2,1,2,2,1,2,1};

// ---------------- setup: rel-derived tables ----------------
__global__ void k_setup(const float* __restrict__ rel, float* __restrict__ tabs) {
    const int t = threadIdx.x;
    float* Rq  = tabs;
    float* Rk  = tabs + 224;
    float* E2q = tabs + 448;
    float* E2k = tabs + 1008;
    float* Tq  = tabs + 1568;
    float* Tk  = tabs + 2016;
    float* Tv  = tabs + 2464;
    for (int idx = t; idx < 448; idx += 256) {
        int which = idx / 224, r = idx % 224;
        int i = r >> 2, c = r & 3;
        const float* src = rel + (which * 4 + c) * 111;
        float s = 0.f;
        for (int tt = 0; tt < 56; ++tt) s += src[i + tt];
        (which ? Rk : Rq)[r] = s;
    }
    for (int idx = t; idx < 1120; idx += 256) {
        int which = idx / 560, r = idx % 560;
        int i = r / 10, p = r % 10;
        const float* sa = rel + (which * 4 + PA[p]) * 111;
        const float* sb = rel + (which * 4 + PB[p]) * 111;
        float s = 0.f;
        for (int tt = 0; tt < 56; ++tt) s += sa[i + tt] * sb[i + tt];
        (which ? E2k : E2q)[r] = s;
    }
    for (int idx = t; idx < 896; idx += 256) {
        int which = idx / 448, r = idx % 448;
        int d = r >> 2, c = r & 3;
        float v = (d < 111) ? rel[(which * 4 + c) * 111 + d] : 0.f;
        (which ? Tk : Tq)[r] = v;
    }
    for (int idx = t; idx < 896; idx += 256) {
        int d = idx >> 3, cc = idx & 7;
        Tv[idx] = (d < 111) ? rel[(8 + cc) * 111 + d] : 0.f;
    }
}

// ---------------- Kernel A: qkv[b][i][o] = w @ x + per-channel stats ----------
__global__ __launch_bounds__(256) void k_qkv(const float* __restrict__ x,
                                             const float* __restrict__ w,
                                             float* __restrict__ qkv,
                                             float* __restrict__ sums) {
    __shared__ float xs[64 * KW];
    __shared__ float wt[64 * 128];
    __shared__ float s1[128], s2[128];
    const int b = blockIdx.x, t = threadIdx.x;

    if (t < 128) { s1[t] = 0.f; s2[t] = 0.f; }
    for (int idx = t; idx < 896; idx += 256) {
        int c = idx / 14, r = idx % 14;
        float4 v = *(const float4*)&x[c * 100352 + b * 56 + r * 4];
        *(float4*)&xs[c * 56 + r * 4] = v;
    }
    for (int idx = t; idx < 2048; idx += 256) {
        int o = idx >> 4, cq = idx & 15;
        float4 v = *(const float4*)&w[o * 64 + cq * 4];
        wt[(cq * 4 + 0) * 128 + o] = v.x;
        wt[(cq * 4 + 1) * 128 + o] = v.y;
        wt[(cq * 4 + 2) * 128 + o] = v.z;
        wt[(cq * 4 + 3) * 128 + o] = v.w;
    }
    __syncthreads();

    if (t < 224) {
        const int ob = t & 31, ib = t >> 5;
        float4 acc[8];
#pragma unroll
        for (int i = 0; i < 8; ++i) acc[i] = make_float4(0.f, 0.f, 0.f, 0.f);
        for (int c = 0; c < 64; ++c) {
            float4 wv = *(const float4*)&wt[c * 128 + (ob << 2)];
            float4 x0 = *(const float4*)&xs[c * 56 + (ib << 3)];
            float4 x1 = *(const float4*)&xs[c * 56 + (ib << 3) + 4];
            float xv[8] = {x0.x, x0.y, x0.z, x0.w, x1.x, x1.y, x1.z, x1.w};
#pragma unroll
            for (int i = 0; i < 8; ++i) {
                acc[i].x += xv[i] * wv.x;
                acc[i].y += xv[i] * wv.y;
                acc[i].z += xv[i] * wv.z;
                acc[i].w += xv[i] * wv.w;
            }
        }
#pragma unroll
        for (int i = 0; i < 8; ++i) {
            *(float4*)&qkv[b * 7168 + (ib * 8 + i) * 128 + ob * 4] = acc[i];
        }
        const float* af = reinterpret_cast<const float*>(acc);
#pragma unroll
        for (int oo = 0; oo < 4; ++oo) {
            float ps = 0.f, ps2 = 0.f;
#pragma unroll
            for (int i = 0; i < 8; ++i) {
                float v = af[i * 4 + oo];
                ps += v; ps2 += v * v;
            }
            atomicAdd(&s1[ob * 4 + oo], ps);
            atomicAdd(&s2[ob * 4 + oo], ps2);
        }
    }
    __syncthreads();
    if (t < 128) {
        float* dst = sums + (b & 7) * 256;       // 8-slot contention split
        atomicAdd(&dst[t], s1[t]);
        atomicAdd(&dst[128 + t], s2[t]);
    }
}

// ---------------- coef finalize (sums 8 slots) ----------------
__global__ void k_coef(const float* __restrict__ sums, const float* __restrict__ g,
                       const float* __restrict__ bb, float* __restrict__ coef,
                       int nch, float invM) {
    int o = blockIdx.x * blockDim.x + threadIdx.x;
    if (o < nch) {
        float a1 = 0.f, a2 = 0.f;
        for (int slot = 0; slot < 8; ++slot) {
            a1 += sums[slot * 2 * nch + o];
            a2 += sums[slot * 2 * nch + nch + o];
        }
        float mean = a1 * invM;
        float var  = fmaxf(a2 * invM - mean * mean, 0.f);
        float sc   = g[o] * rsqrtf(var + EPS);
        coef[o] = sc;
        coef[nch + o] = bb[o] - mean * sc;
    }
}

// ---------------- sim stats via Gram matrices (one wave per (b,g)) -----------
__global__ __launch_bounds__(256) void k_simstats(const float* __restrict__ qkv,
                                                  const float* __restrict__ qcoef,
                                                  const float* __restrict__ Rq,
                                                  const float* __restrict__ Rk,
                                                  const float* __restrict__ E2q,
                                                  const float* __restrict__ E2k,
                                                  float* __restrict__ ssum) {
    const int wid = threadIdx.x >> 6, lane = threadIdx.x & 63;
    const int unit = blockIdx.x * 4 + wid;
    const int b = unit >> 3, g = unit & 7;
    const int iL = lane < 56 ? lane : 55;
    const float valid = lane < 56 ? 1.f : 0.f;

    const float* row = qkv + b * 7168 + iL * 128 + g * 16;
    float4 q4 = *(const float4*)(row);
    float4 k4 = *(const float4*)(row + 4);
    const float4 aq = *(const float4*)&qcoef[g * 16];
    const float4 ak = *(const float4*)&qcoef[g * 16 + 4];
    const float4 cq = *(const float4*)&qcoef[QKV_CH + g * 16];
    const float4 ck = *(const float4*)&qcoef[QKV_CH + g * 16 + 4];
    float qv[4], kv[4];
    qv[0] = (q4.x * aq.x + cq.x) * valid;
    qv[1] = (q4.y * aq.y + cq.y) * valid;
    qv[2] = (q4.z * aq.z + cq.z) * valid;
    qv[3] = (q4.w * aq.w + cq.w) * valid;
    kv[0] = (k4.x * ak.x + ck.x) * valid;
    kv[1] = (k4.y * ak.y + ck.y) * valid;
    kv[2] = (k4.z * ak.z + ck.z) * valid;
    kv[3] = (k4.w * ak.w + ck.w) * valid;

    float4 rq = *(const float4*)&Rq[iL * 4];
    float4 rk = *(const float4*)&Rk[iL * 4];
    float e2q[10], e2k[10];
#pragma unroll
    for (int p = 0; p < 10; ++p) { e2q[p] = E2q[iL * 10 + p]; e2k[p] = E2k[iL * 10 + p]; }

    float red[32];
#pragma unroll
    for (int c = 0; c < 4; ++c) { red[c] = qv[c]; red[4 + c] = kv[c]; }
#pragma unroll
    for (int p = 0; p < 10; ++p) {
        red[8 + p]  = qv[PA[p]] * qv[PB[p]];
        red[18 + p] = kv[PA[p]] * kv[PB[p]];
    }
    {
        float rqa[4] = {rq.x, rq.y, rq.z, rq.w};
        float rka[4] = {rk.x, rk.y, rk.z, rk.w};
        float pq = 0.f, pk = 0.f, pq2 = 0.f, pk2 = 0.f;
#pragma unroll
        for (int c = 0; c < 4; ++c) { pq += qv[c] * rqa[c]; pk += kv[c] * rka[c]; }
#pragma unroll
        for (int p = 0; p < 10; ++p) {
            pq2 += PMf[p] * red[8 + p]  * e2q[p];
            pk2 += PMf[p] * red[18 + p] * e2k[p];
        }
        red[28] = pq; red[29] = pk; red[30] = pq2; red[31] = pk2;
    }
#pragma unroll
    for (int v = 0; v < 32; ++v) {
        float xv = red[v];
#pragma unroll
        for (int mk = 1; mk < 64; mk <<= 1) xv += __shfl_xor(xv, mk);
        red[v] = xv;
    }
    float sqk = 0.f, sqk2 = 0.f;
#pragma unroll
    for (int c = 0; c < 4; ++c) sqk += red[c] * red[4 + c];
#pragma unroll
    for (int p = 0; p < 10; ++p) sqk2 += PMf[p] * red[8 + p] * red[18 + p];
    if (lane == 0) {
        float* ss = ssum + (blockIdx.x & 7) * 48;    // 8-slot split
        atomicAdd(&ss[g], sqk);
        atomicAdd(&ss[8 + g], 0.1f * red[28]);
        atomicAdd(&ss[16 + g], 0.1f * red[29]);
        atomicAdd(&ss[SIM_CH + g], sqk2);
        atomicAdd(&ss[SIM_CH + 8 + g], 0.01f * red[30]);
        atomicAdd(&ss[SIM_CH + 16 + g], 0.01f * red[31]);
    }
}

// ---------------- attention: one wave per (b,g), lane = i, diagonal s-loop ----
// No srow array (no-max softmax: S is BN-normalized, |S| small, fp32 exp safe).
// LDS: channel-pair-major extended arrays -> float2 stride-8B reads, conflict-free.
__global__ __launch_bounds__(256) void k_attn(const float* __restrict__ qkv,
                                              const float* __restrict__ qcoef,
                                              const float* __restrict__ scoef,
                                              const float* __restrict__ Tq,
                                              const float* __restrict__ Tk,
                                              const float* __restrict__ Tv,
                                              float* __restrict__ so,
                                              float* __restrict__ osums) {
    __shared__ float sm[4 * 1344];
    const int wid = threadIdx.x >> 6, lane = threadIdx.x & 63;
    const int unit = blockIdx.x * 4 + wid;
    const int b = unit >> 3, g = unit & 7;
    float* sl = sm + wid * 1344;    // rows of 224: k01,k23,v01,v23,v45,v67 (ext 112)
    const int iL = lane < 56 ? lane : 55;

    const float* row = qkv + b * 7168 + iL * 128 + g * 16;
    float4 q4  = *(const float4*)(row);
    float4 k4  = *(const float4*)(row + 4);
    float4 va4 = *(const float4*)(row + 8);
    float4 vb4 = *(const float4*)(row + 12);
    const float4 a0 = *(const float4*)&qcoef[g * 16];
    const float4 a1 = *(const float4*)&qcoef[g * 16 + 4];
    const float4 a2 = *(const float4*)&qcoef[g * 16 + 8];
    const float4 a3 = *(const float4*)&qcoef[g * 16 + 12];
    const float4 c0 = *(const float4*)&qcoef[QKV_CH + g * 16];
    const float4 c1 = *(const float4*)&qcoef[QKV_CH + g * 16 + 4];
    const float4 c2 = *(const float4*)&qcoef[QKV_CH + g * 16 + 8];
    const float4 c3 = *(const float4*)&qcoef[QKV_CH + g * 16 + 12];
    float4 qh;
    qh.x = q4.x * a0.x + c0.x;  qh.y = q4.y * a0.y + c0.y;
    qh.z = q4.z * a0.z + c0.z;  qh.w = q4.w * a0.w + c0.w;
    if (lane < 56) {
        float2 k01 = make_float2(k4.x * a1.x + c1.x, k4.y * a1.y + c1.y);
        float2 k23 = make_float2(k4.z * a1.z + c1.z, k4.w * a1.w + c1.w);
        float2 v01 = make_float2(va4.x * a2.x + c2.x, va4.y * a2.y + c2.y);
        float2 v23 = make_float2(va4.z * a2.z + c2.z, va4.w * a2.w + c2.w);
        float2 v45 = make_float2(vb4.x * a3.x + c3.x, vb4.y * a3.y + c3.y);
        float2 v67 = make_float2(vb4.z * a3.z + c3.z, vb4.w * a3.w + c3.w);
        *(float2*)&sl[          iL * 2] = k01;  *(float2*)&sl[          (iL + 56) * 2] = k01;
        *(float2*)&sl[ 224 +    iL * 2] = k23;  *(float2*)&sl[ 224 +    (iL + 56) * 2] = k23;
        *(float2*)&sl[ 448 +    iL * 2] = v01;  *(float2*)&sl[ 448 +    (iL + 56) * 2] = v01;
        *(float2*)&sl[ 672 +    iL * 2] = v23;  *(float2*)&sl[ 672 +    (iL + 56) * 2] = v23;
        *(float2*)&sl[ 896 +    iL * 2] = v45;  *(float2*)&sl[ 896 +    (iL + 56) * 2] = v45;
        *(float2*)&sl[1120 +    iL * 2] = v67;  *(float2*)&sl[1120 +    (iL + 56) * 2] = v67;
    }
    __builtin_amdgcn_s_waitcnt(0);  // drain own lgkm before reads (same wave; cheap)

    const float aqk = scoef[g];
    const float aqr = scoef[8 + g] * 0.1f;
    const float akr = scoef[16 + g] * 0.1f;
    const float cc  = scoef[SIM_CH + g] + scoef[SIM_CH + 8 + g] + scoef[SIM_CH + 16 + g];

    float l = 0.f;
    float sv[8], se[8];
#pragma unroll
    for (int c = 0; c < 8; ++c) { sv[c] = 0.f; se[c] = 0.f; }

#pragma unroll 7
    for (int s = 0; s < 56; ++s) {
        const int p2 = (iL + s) * 2;
        const float2 kk01 = *(const float2*)&sl[p2];
        const float2 kk23 = *(const float2*)&sl[224 + p2];
        // wave-uniform rel rows (scalar loads)
        const float4 tql = *(const float4*)&Tq[(55 - s) * 4];
        const float4 tqh = *(const float4*)&Tq[(111 - s) * 4];
        const float4 tkl = *(const float4*)&Tk[(55 + s) * 4];
        const float4 tkh = *(const float4*)&Tk[(s > 0 ? s - 1 : 0) * 4];
        const bool wrap = (iL + s) >= 56;
        float rq0 = wrap ? tqh.x : tql.x, rq1 = wrap ? tqh.y : tql.y;
        float rq2 = wrap ? tqh.z : tql.z, rq3 = wrap ? tqh.w : tql.w;
        float rk0 = wrap ? tkh.x : tkl.x, rk1 = wrap ? tkh.y : tkl.y;
        float rk2 = wrap ? tkh.z : tkl.z, rk3 = wrap ? tkh.w : tkl.w;
        float qk = qh.x * kk01.x + qh.y * kk01.y + qh.z * kk23.x + qh.w * kk23.y;
        float qr = qh.x * rq0 + qh.y * rq1 + qh.z * rq2 + qh.w * rq3;
        float kr = kk01.x * rk0 + kk01.y * rk1 + kk23.x * rk2 + kk23.y * rk3;
        float e = __expf(qk * aqk + qr * aqr + kr * akr + cc);
        l += e;
        const float2 v01 = *(const float2*)&sl[448 + p2];
        const float2 v23 = *(const float2*)&sl[672 + p2];
        const float2 v45 = *(const float2*)&sl[896 + p2];
        const float2 v67 = *(const float2*)&sl[1120 + p2];
        sv[0] += e * v01.x; sv[1] += e * v01.y;
        sv[2] += e * v23.x; sv[3] += e * v23.y;
        sv[4] += e * v45.x; sv[5] += e * v45.y;
        sv[6] += e * v67.x; sv[7] += e * v67.y;
        const float4 tv1l = *(const float4*)&Tv[(55 - s) * 8];
        const float4 tv2l = *(const float4*)&Tv[(55 - s) * 8 + 4];
        const float4 tv1h = *(const float4*)&Tv[(111 - s) * 8];
        const float4 tv2h = *(const float4*)&Tv[(111 - s) * 8 + 4];
        se[0] += e * (wrap ? tv1h.x : tv1l.x);
        se[1] += e * (wrap ? tv1h.y : tv1l.y);
        se[2] += e * (wrap ? tv1h.z : tv1l.z);
        se[3] += e * (wrap ? tv1h.w : tv1l.w);
        se[4] += e * (wrap ? tv2h.x : tv2l.x);
        se[5] += e * (wrap ? tv2h.y : tv2l.y);
        se[6] += e * (wrap ? tv2h.z : tv2l.z);
        se[7] += e * (wrap ? tv2h.w : tv2l.w);
    }
    const float inv = 1.f / l;
    float osv[8], ose[8];
#pragma unroll
    for (int c = 0; c < 8; ++c) {
        osv[c] = sv[c] * inv;
        ose[c] = se[c] * (0.1f * inv);
    }
    if (lane < 56) {
        float* op = so + b * 7168 + g * 16 * 56 + iL;
#pragma unroll
        for (int c = 0; c < 8; ++c) {
            op[(2 * c) * 56]     = osv[c];
            op[(2 * c + 1) * 56] = ose[c];
        }
    }
    const float valid = lane < 56 ? 1.f : 0.f;
    float red[32];
#pragma unroll
    for (int c = 0; c < 8; ++c) {
        red[c]      = osv[c] * valid;
        red[8 + c]  = ose[c] * valid;
        red[16 + c] = osv[c] * osv[c] * valid;
        red[24 + c] = ose[c] * ose[c] * valid;
    }
#pragma unroll
    for (int v = 0; v < 32; ++v) {
        float xv = red[v];
#pragma unroll
        for (int mk = 1; mk < 64; mk <<= 1) xv += __shfl_xor(xv, mk);
        red[v] = xv;
    }
    if (lane == 0) {
        float* dst = osums + (blockIdx.x & 7) * 256;   // 8-slot split
#pragma unroll
        for (int c = 0; c < 8; ++c) {
            atomicAdd(&dst[g * 16 + 2 * c],           red[c]);
            atomicAdd(&dst[g * 16 + 2 * c + 1],       red[8 + c]);
            atomicAdd(&dst[128 + g * 16 + 2 * c],     red[16 + c]);
            atomicAdd(&dst[128 + g * 16 + 2 * c + 1], red[24 + c]);
        }
    }
}

// ---------------- out-BN + pair-sum + transpose store ----------------
__global__ __launch_bounds__(256) void k_out(const float* __restrict__ so,
                                             const float* __restrict__ ocoef,
                                             float* __restrict__ out) {
    int idx = blockIdx.x * 256 + threadIdx.x;
    int t = idx % KW;
    int rest = idx / KW;
    int h = rest % KW;
    int rest2 = rest / KW;
    int d = rest2 & 31;
    int oc = rest2 >> 5;
    int b = d * KW + h;
    int o0 = 2 * oc;
    float v0 = so[(size_t)b * 7168 + o0 * KW + t];
    float v1 = so[(size_t)b * 7168 + (o0 + 1) * KW + t];
    v0 = v0 * ocoef[o0]     + ocoef[QKV_CH + o0];
    v1 = v1 * ocoef[o0 + 1] + ocoef[QKV_CH + o0 + 1];
    out[idx] = v0 + v1;
}

extern "C" void kernel_launch(void* const* d_in, const int* in_sizes, int n_in,
                              void* d_out, int out_size, void* d_ws, size_t ws_size,
                              hipStream_t stream) {
    const float* x     = (const float*)d_in[0];
    const float* wqkv  = (const float*)d_in[1];
    const float* rel   = (const float*)d_in[2];
    const float* g_qkv = (const float*)d_in[3];
    const float* b_qkv = (const float*)d_in[4];
    const float* g_sim = (const float*)d_in[5];
    const float* b_sim = (const float*)d_in[6];
    const float* g_out = (const float*)d_in[7];
    const float* b_out = (const float*)d_in[8];
    float* out = (float*)d_out;
    float* ws = (float*)d_ws;

    float* qkv_raw  = ws;                       // [b][i][o]
    float* so_raw   = ws + 12845056;            // [b][o][i]
    float* stats    = ws + 25690112;
    float* qkv_sums = stats;                    // 8 x 256
    float* sim_sums = stats + 2048;             // 8 x 48
    float* out_sums = stats + 2432;             // 8 x 256
    float* qkv_coef = stats + 4480;             // 256
    float* sim_coef = stats + 4736;             // 48
    float* out_coef = stats + 4784;             // 256
    float* tabs     = stats + 5040;             // rel tables (3360)
    float* Rq  = tabs;
    float* Rk  = tabs + 224;
    float* E2q = tabs + 448;
    float* E2k = tabs + 1008;
    float* Tq  = tabs + 1568;
    float* Tk  = tabs + 2016;
    float* Tv  = tabs + 2464;

    hipMemsetAsync(stats, 0, 4480 * sizeof(float), stream);
    k_setup<<<1, 256, 0, stream>>>(rel, tabs);

    k_qkv<<<NB, 256, 0, stream>>>(x, wqkv, qkv_raw, qkv_sums);
    k_coef<<<1, 128, 0, stream>>>(qkv_sums, g_qkv, b_qkv, qkv_coef, QKV_CH,
                                  1.0f / 100352.0f);
    k_simstats<<<3584, 256, 0, stream>>>(qkv_raw, qkv_coef, Rq, Rk, E2q, E2k,
                                         sim_sums);
    k_coef<<<1, 128, 0, stream>>>(sim_sums, g_sim, b_sim, sim_coef, SIM_CH,
                                  1.0f / 5619712.0f);
    k_attn<<<3584, 256, 0, stream>>>(qkv_raw, qkv_coef, sim_coef, Tq, Tk, Tv,
                                     so_raw, out_sums);
    k_coef<<<1, 128, 0, stream>>>(out_sums, g_out, b_out, out_coef, QKV_CH,
                                  1.0f / 100352.0f);
    k_out<<<25088, 256, 0, stream>>>(so_raw, out_coef, out);
}